// Round 9
// baseline (143.358 us; speedup 1.0000x reference)
//
#include <hip/hip_runtime.h>
#include <hip/hip_bf16.h>

// MultiHeadAttention B=4 S=2048 E=512 H=8 D=64, causal. Inputs fp32, output fp32.
//   proj: X @ W^T per head; Qp pre-scaled by log2(e)/8; Qp/Kp [bh][s][d], Vt [bh][d][s]
//   attn: transposed flash attention with 32x32x16 MFMA; 512-thread blocks,
//         4 kv-groups x 2 waves (each wave = 32 q cols); P^T B-frags built via
//         cvt_pk_bf16 + permlane32_swap (ZERO LDS ops for redistribution);
//         single-buffered per-group K/V LDS w/ T14 write-late; 4-way flash merge;
//         LPT grid + XCD-affine bh. Round-8 analysis: LDS-pipe-bound -> this cuts
//         LDS wave-ops/block-iter ~4x (bpermute 128->0, frag reads 128->64).
//   fc:   [8192,512] @ Wfc^T + bias -> fp32 out
#define S_LEN 2048
#define EMB 512
#define NH 8
#define HD 64

typedef __bf16 bf16x8 __attribute__((ext_vector_type(8)));
typedef __bf16 bf16x4 __attribute__((ext_vector_type(4)));
typedef float f32x4 __attribute__((ext_vector_type(4)));
typedef float f32x16 __attribute__((ext_vector_type(16)));
typedef int i32x4 __attribute__((ext_vector_type(4)));

__device__ __forceinline__ unsigned swz(unsigned byteoff, unsigned row) {
    return byteoff ^ ((row & 7u) << 4);
}

// v_permlane32_swap_b32: a' = {a.lo | b.lo(placed hi)}, b' = {a.hi(placed lo) | b.hi}
__device__ __forceinline__ void plswap(int& a, int& b) {
#if __has_builtin(__builtin_amdgcn_permlane32_swap)
    auto r = __builtin_amdgcn_permlane32_swap(a, b, false, false);
    a = r[0];
    b = r[1];
#else
    asm("v_permlane32_swap_b32 %0, %1" : "+v"(a), "+v"(b));
#endif
}

__global__ __launch_bounds__(256) void proj_kernel(
    const float* __restrict__ qin, const float* __restrict__ kin, const float* __restrict__ vin,
    const float* __restrict__ Wq, const float* __restrict__ Wk, const float* __restrict__ Wv,
    __bf16* __restrict__ Qp, __bf16* __restrict__ Kp, __bf16* __restrict__ Vt)
{
    __shared__ alignas(16) unsigned char xb[3][8192]; // 64x64 bf16 tiles (q,k,v rows), swizzled
    __shared__ alignas(16) unsigned char tb[8192];    // v-proj output tile for transpose, linear
    const int bh = blockIdx.y;
    const int b = bh >> 3, h = bh & 7;
    const int sblk = blockIdx.x << 6;
    const int tid = threadIdx.x;
    const int w = tid >> 6, l = tid & 63;
    const int col = l & 15, g = l >> 4;
    const float K1 = 0.18033688011112042f; // log2(e)/8 folded into Qp

    const float* srcs[3] = {qin, kin, vin};
    #pragma unroll
    for (int p = 0; p < 3; ++p) {
        const float* src = srcs[p] + ((size_t)b * S_LEN + sblk) * EMB + h * HD;
        #pragma unroll
        for (int it = 0; it < 4; ++it) {
            int c = tid + it * 256;            // 1024 float4 chunks = 64 rows x 16
            int row = c >> 4, c4 = c & 15;
            float4 f = *reinterpret_cast<const float4*>(src + (size_t)row * EMB + c4 * 4);
            bf16x4 t;
            t[0] = (__bf16)f.x; t[1] = (__bf16)f.y; t[2] = (__bf16)f.z; t[3] = (__bf16)f.w;
            *reinterpret_cast<bf16x4*>(&xb[p][swz(row * 128 + c4 * 8, row)]) = t;
        }
    }
    __syncthreads();

    const float* Ws[3] = {Wq, Wk, Wv};
    #pragma unroll
    for (int p = 0; p < 3; ++p) {
        bf16x8 wf[4][2];
        #pragma unroll
        for (int nf = 0; nf < 4; ++nf)
            #pragma unroll
            for (int ks = 0; ks < 2; ++ks) {
                const float* base = Ws[p] + (nf * 16 + col) * HD + ks * 32 + g * 8;
                float4 f0 = *reinterpret_cast<const float4*>(base);
                float4 f1 = *reinterpret_cast<const float4*>(base + 4);
                bf16x8 r;
                r[0] = (__bf16)f0.x; r[1] = (__bf16)f0.y; r[2] = (__bf16)f0.z; r[3] = (__bf16)f0.w;
                r[4] = (__bf16)f1.x; r[5] = (__bf16)f1.y; r[6] = (__bf16)f1.z; r[7] = (__bf16)f1.w;
                wf[nf][ks] = r;
            }
        int arow = w * 16 + col;
        bf16x8 a0 = *reinterpret_cast<const bf16x8*>(&xb[p][swz(arow * 128 + g * 16, arow)]);
        bf16x8 a1 = *reinterpret_cast<const bf16x8*>(&xb[p][swz(arow * 128 + 64 + g * 16, arow)]);
        f32x4 acc[4];
        #pragma unroll
        for (int nf = 0; nf < 4; ++nf) acc[nf] = (f32x4){0.f, 0.f, 0.f, 0.f};
        #pragma unroll
        for (int nf = 0; nf < 4; ++nf) {
            acc[nf] = __builtin_amdgcn_mfma_f32_16x16x32_bf16(a0, wf[nf][0], acc[nf], 0, 0, 0);
            acc[nf] = __builtin_amdgcn_mfma_f32_16x16x32_bf16(a1, wf[nf][1], acc[nf], 0, 0, 0);
        }
        if (p < 2) {
            __bf16* dst = (p == 0 ? Qp : Kp);
            const float s0 = (p == 0) ? K1 : 1.0f; // fold softmax scale into Q
            #pragma unroll
            for (int nf = 0; nf < 4; ++nf)
                #pragma unroll
                for (int r = 0; r < 4; ++r) {
                    int srow = sblk + w * 16 + g * 4 + r;
                    dst[((size_t)bh * S_LEN + srow) * HD + nf * 16 + col] =
                        (__bf16)(acc[nf][r] * s0);
                }
        } else {
            #pragma unroll
            for (int nf = 0; nf < 4; ++nf)
                #pragma unroll
                for (int r = 0; r < 4; ++r) {
                    int srow = w * 16 + g * 4 + r;
                    *reinterpret_cast<__bf16*>(&tb[(srow * 64 + nf * 16 + col) * 2]) =
                        (__bf16)acc[nf][r];
                }
        }
    }
    __syncthreads();
    {
        int e = tid & 63, sc = tid >> 6;
        bf16x8 lo, hi;
        #pragma unroll
        for (int i = 0; i < 8; ++i)
            lo[i] = *reinterpret_cast<const __bf16*>(&tb[((sc * 16 + i) * 64 + e) * 2]);
        #pragma unroll
        for (int i = 0; i < 8; ++i)
            hi[i] = *reinterpret_cast<const __bf16*>(&tb[((sc * 16 + 8 + i) * 64 + e) * 2]);
        __bf16* dst = Vt + ((size_t)bh * HD + e) * S_LEN + sblk + sc * 16;
        *reinterpret_cast<bf16x8*>(dst) = lo;
        *reinterpret_cast<bf16x8*>(dst + 8) = hi;
    }
}

__global__ __launch_bounds__(512, 4) void attn_kernel(
    const __bf16* __restrict__ Qp, const __bf16* __restrict__ Kp,
    const __bf16* __restrict__ Vt, __bf16* __restrict__ Oa)
{
    // per-group {K 8KB, V 8KB} single-buffered; reused as merge buffers after loop
    __shared__ alignas(16) unsigned char smem[65536];
    const int l_id = blockIdx.x;
    const int bh = l_id & 31;            // XCD-affine: same-bh blocks share l%8
    const int qt = 31 - (l_id >> 5);     // LPT: longest blocks dispatched first
    const int b = bh >> 3, h = bh & 7;
    const int tid = threadIdx.x;
    const int w = tid >> 6, l = tid & 63;
    const int g2 = w >> 1, qh = w & 1;   // kv-group (0..3), q-half (0..1)
    const int c32 = l & 31, hi = l >> 5;

    unsigned char* kbg = smem + g2 * 16384;
    unsigned char* vbg = kbg + 8192;

    const unsigned char* kgb =
        reinterpret_cast<const unsigned char*>(Kp + (size_t)bh * S_LEN * HD);
    const unsigned char* vgb =
        reinterpret_cast<const unsigned char*>(Vt + (size_t)bh * HD * S_LEN);
    const int ts = tid & 127;            // group-local staging id (128 thr/group)

    // Q B-frag: lane holds Q[q = qt*64+qh*32+c32][d = ks*16 + hi*8 + e]
    bf16x8 qf[4];
    {
        const __bf16* qb =
            Qp + ((size_t)bh * S_LEN + qt * 64 + qh * 32 + c32) * HD + hi * 8;
        #pragma unroll
        for (int ks = 0; ks < 4; ++ks) qf[ks] = *reinterpret_cast<const bf16x8*>(qb + ks * 16);
    }
    // O^T acc: lane holds O^T[d = nf*32+(r&3)+8(r>>2)+4hi][q = c32]
    f32x16 oacc[2];
    #pragma unroll
    for (int nf = 0; nf < 2; ++nf)
        #pragma unroll
        for (int r = 0; r < 16; ++r) oacc[nf][r] = 0.f;
    float m = -1e30f, lsum = 0.f;

    uint4 kr[4], vr[4];
    if (g2 <= qt) { // prologue: stage this group's first tile (t = g2)
        const unsigned char* kg = kgb + (size_t)g2 * 8192;
        const unsigned char* vg = vgb + (size_t)g2 * 128;
        #pragma unroll
        for (int j = 0; j < 4; ++j) {
            int c = ts + 128 * j, row = c >> 3, off = (c & 7) * 16;
            kr[j] = *reinterpret_cast<const uint4*>(kg + row * 128 + off);
            vr[j] = *reinterpret_cast<const uint4*>(vg + (size_t)row * 4096 + off);
        }
        #pragma unroll
        for (int j = 0; j < 4; ++j) {
            int c = ts + 128 * j, row = c >> 3, off = (c & 7) * 16;
            *reinterpret_cast<uint4*>(kbg + swz(row * 128 + off, row)) = kr[j];
            *reinterpret_cast<uint4*>(vbg + swz(row * 128 + off, row)) = vr[j];
        }
    }
    __syncthreads();

    const int niter = (qt >> 2) + 1;
    #pragma unroll 1
    for (int i = 0; i < niter; ++i) {
        const int t = 4 * i + g2;
        const bool active = (t <= qt);
        const bool pfv = (t + 4 <= qt);
        if (pfv) { // T14: issue next tile's loads; latency hides under compute
            const unsigned char* kg = kgb + (size_t)(t + 4) * 8192;
            const unsigned char* vg = vgb + (size_t)(t + 4) * 128;
            #pragma unroll
            for (int j = 0; j < 4; ++j) {
                int c = ts + 128 * j, row = c >> 3, off = (c & 7) * 16;
                kr[j] = *reinterpret_cast<const uint4*>(kg + row * 128 + off);
                vr[j] = *reinterpret_cast<const uint4*>(vg + (size_t)row * 4096 + off);
            }
        }
        if (active) {
            // S^T = K Q^T : lane holds S^T[kv = nf*32+(r&3)+8(r>>2)+4hi][q = c32]
            f32x16 sfa[2];
            #pragma unroll
            for (int nf = 0; nf < 2; ++nf)
                #pragma unroll
                for (int r = 0; r < 16; ++r) sfa[nf][r] = 0.f;
            #pragma unroll
            for (int nf = 0; nf < 2; ++nf) {
                int row = nf * 32 + c32;
                #pragma unroll
                for (int ks = 0; ks < 4; ++ks) {
                    bf16x8 kf = *reinterpret_cast<const bf16x8*>(
                        kbg + swz(row * 128 + ks * 32 + hi * 16, row));
                    sfa[nf] =
                        __builtin_amdgcn_mfma_f32_32x32x16_bf16(kf, qf[ks], sfa[nf], 0, 0, 0);
                }
            }
            if (t == qt) { // diagonal: mask kv_local > q_local
                const int qloc = qh * 32 + c32;
                #pragma unroll
                for (int nf = 0; nf < 2; ++nf)
                    #pragma unroll
                    for (int r = 0; r < 16; ++r) {
                        int kvloc = nf * 32 + (r & 3) + 8 * (r >> 2) + 4 * hi;
                        if (kvloc > qloc) sfa[nf][r] = -1e30f;
                    }
            }
            // per-q max: 31 local fmax + 1 cross-half shuffle
            float rmax = sfa[0][0];
            #pragma unroll
            for (int nf = 0; nf < 2; ++nf)
                #pragma unroll
                for (int r = 0; r < 16; ++r) rmax = fmaxf(rmax, sfa[nf][r]);
            rmax = fmaxf(rmax, __shfl_xor(rmax, 32));
            float mn = fmaxf(m, rmax);
            float sc = __builtin_exp2f(m - mn);
            m = mn;
            float rsum = 0.f;
            int wds[16];
            #pragma unroll
            for (int nf = 0; nf < 2; ++nf) {
                #pragma unroll
                for (int i2 = 0; i2 < 8; ++i2) {
                    float p0 = __builtin_exp2f(sfa[nf][2 * i2] - m);
                    float p1 = __builtin_exp2f(sfa[nf][2 * i2 + 1] - m);
                    rsum += p0 + p1;
                    asm("v_cvt_pk_bf16_f32 %0, %1, %2"
                        : "=v"(wds[nf * 8 + i2]) : "v"(p0), "v"(p1));
                }
            }
            lsum = lsum * sc + rsum;
            // P^T B-frags via permlane32_swap: swap(w0,w2)->(x0,x2), swap(w1,w3)->(x1,x3)
            bf16x8 pfrag[4];
            #pragma unroll
            for (int ks = 0; ks < 4; ++ks) {
                int o = (ks >> 1) * 8 + (ks & 1) * 4;
                int a0 = wds[o + 0], a1 = wds[o + 1], a2 = wds[o + 2], a3 = wds[o + 3];
                plswap(a0, a2);
                plswap(a1, a3);
                i32x4 pw;
                pw[0] = a0; pw[1] = a1; pw[2] = a2; pw[3] = a3;
                pfrag[ks] = *reinterpret_cast<bf16x8*>(&pw);
            }
            #pragma unroll
            for (int nf = 0; nf < 2; ++nf)
                #pragma unroll
                for (int r = 0; r < 16; ++r) oacc[nf][r] *= sc;
            // O^T += V^T P^T
            #pragma unroll
            for (int nf = 0; nf < 2; ++nf) {
                int row = nf * 32 + c32;
                #pragma unroll
                for (int ks = 0; ks < 4; ++ks) {
                    bf16x8 vf = *reinterpret_cast<const bf16x8*>(
                        vbg + swz(row * 128 + ks * 32 + hi * 16, row));
                    oacc[nf] =
                        __builtin_amdgcn_mfma_f32_32x32x16_bf16(vf, pfrag[ks], oacc[nf], 0, 0, 0);
                }
            }
        }
        __syncthreads(); // all reads of this buffer done
        if (pfv) {       // write-late into the same buffer
            #pragma unroll
            for (int j = 0; j < 4; ++j) {
                int c = ts + 128 * j, row = c >> 3, off = (c & 7) * 16;
                *reinterpret_cast<uint4*>(kbg + swz(row * 128 + off, row)) = kr[j];
                *reinterpret_cast<uint4*>(vbg + swz(row * 128 + off, row)) = vr[j];
            }
        }
        __syncthreads();
    }

    // 4-way flash merge: groups 1..3 publish partials; group 0 merges + stores.
    // obuf: 6 regions x 8KB (reg-major, lane-contiguous = conflict-free);
    // m/lsum at float offset 12288.
    float* mg = reinterpret_cast<float*>(smem);
    const int idx = (g2 - 1) * 2 + qh;
    if (g2 != 0) {
        #pragma unroll
        for (int nf = 0; nf < 2; ++nf)
            #pragma unroll
            for (int r = 0; r < 16; ++r)
                mg[idx * 2048 + (nf * 16 + r) * 64 + l] = oacc[nf][r];
        mg[12288 + idx * 128 + l] = m;
        mg[12288 + idx * 128 + 64 + l] = lsum;
    }
    __syncthreads();
    if (g2 == 0) {
        #pragma unroll 1
        for (int gg = 1; gg < 4; ++gg) {
            const int ix = (gg - 1) * 2 + qh;
            float mB = mg[12288 + ix * 128 + l];
            float lB = mg[12288 + ix * 128 + 64 + l];
            float M = fmaxf(m, mB);
            float eA = __builtin_exp2f(m - M);
            float eB = __builtin_exp2f(mB - M);
            m = M;
            lsum = eA * lsum + eB * lB;
            #pragma unroll
            for (int nf = 0; nf < 2; ++nf)
                #pragma unroll
                for (int r = 0; r < 16; ++r)
                    oacc[nf][r] = eA * oacc[nf][r] + eB * mg[ix * 2048 + (nf * 16 + r) * 64 + l];
        }
        lsum += __shfl_xor(lsum, 32);
        float inv = 1.0f / lsum;
        const int q = qt * 64 + qh * 32 + c32;
        __bf16* op = Oa + ((size_t)b * S_LEN + q) * EMB + h * HD;
        #pragma unroll
        for (int nf = 0; nf < 2; ++nf)
            #pragma unroll
            for (int rq = 0; rq < 4; ++rq) {
                bf16x4 o4;
                #pragma unroll
                for (int e = 0; e < 4; ++e) o4[e] = (__bf16)(oacc[nf][rq * 4 + e] * inv);
                *reinterpret_cast<bf16x4*>(op + nf * 32 + rq * 8 + hi * 4) = o4;
            }
    }
}

__global__ __launch_bounds__(256) void fc_kernel(
    const __bf16* __restrict__ A,   // Oattn [B*S][E] bf16
    const float* __restrict__ Wfc,  // [E][E] fp32, row-major (n, k)
    const float* __restrict__ bfc,  // [E]
    float* __restrict__ out)        // [B*S][E] fp32
{
    __shared__ alignas(16) unsigned char ab[8192]; // A tile 64x64 bf16, swizzled
    __shared__ alignas(16) unsigned char bb[8192]; // W tile 64x64 bf16, swizzled
    const int r0 = blockIdx.x << 6;
    const int n0 = blockIdx.y << 6;
    const int tid = threadIdx.x;
    const int w = tid >> 6, l = tid & 63;
    const int col = l & 15, g = l >> 4;

    f32x4 acc[4];
    #pragma unroll
    for (int nf = 0; nf < 4; ++nf) acc[nf] = (f32x4){0.f, 0.f, 0.f, 0.f};

    for (int kc = 0; kc < 8; ++kc) {
        __syncthreads();
        #pragma unroll
        for (int it = 0; it < 2; ++it) {
            int c = tid + it * 256;
            int row = c >> 3, o = (c & 7) * 16;
            uint4 d = *reinterpret_cast<const uint4*>(
                reinterpret_cast<const unsigned char*>(A) +
                ((size_t)(r0 + row) * EMB + kc * 64) * 2 + o);
            *reinterpret_cast<uint4*>(&ab[swz(row * 128 + o, row)]) = d;
        }
        #pragma unroll
        for (int it = 0; it < 4; ++it) {
            int c = tid + it * 256;
            int row = c >> 4, c4 = c & 15;
            float4 f = *reinterpret_cast<const float4*>(
                Wfc + (size_t)(n0 + row) * EMB + kc * 64 + c4 * 4);
            bf16x4 t;
            t[0] = (__bf16)f.x; t[1] = (__bf16)f.y; t[2] = (__bf16)f.z; t[3] = (__bf16)f.w;
            *reinterpret_cast<bf16x4*>(&bb[swz(row * 128 + c4 * 8, row)]) = t;
        }
        __syncthreads();
        int arow = w * 16 + col;
        #pragma unroll
        for (int ks = 0; ks < 2; ++ks) {
            bf16x8 af = *reinterpret_cast<const bf16x8*>(
                &ab[swz(arow * 128 + ks * 64 + g * 16, arow)]);
            #pragma unroll
            for (int nf = 0; nf < 4; ++nf) {
                int brow = nf * 16 + col;
                bf16x8 bf = *reinterpret_cast<const bf16x8*>(
                    &bb[swz(brow * 128 + ks * 64 + g * 16, brow)]);
                acc[nf] = __builtin_amdgcn_mfma_f32_16x16x32_bf16(af, bf, acc[nf], 0, 0, 0);
            }
        }
    }
    #pragma unroll
    for (int nf = 0; nf < 4; ++nf) {
        float bias = bfc[n0 + nf * 16 + col];
        #pragma unroll
        for (int r = 0; r < 4; ++r) {
            int row = r0 + w * 16 + g * 4 + r;
            out[(size_t)row * EMB + n0 + nf * 16 + col] = acc[nf][r] + bias;
        }
    }
}

extern "C" void kernel_launch(void* const* d_in, const int* in_sizes, int n_in,
                              void* d_out, int out_size, void* d_ws, size_t ws_size,
                              hipStream_t stream) {
    const float* q   = (const float*)d_in[0];
    const float* k   = (const float*)d_in[1];
    const float* v   = (const float*)d_in[2];
    const float* Wq  = (const float*)d_in[3];
    const float* Wk  = (const float*)d_in[4];
    const float* Wv  = (const float*)d_in[5];
    const float* Wfc = (const float*)d_in[6];
    const float* bfc = (const float*)d_in[7];
    float* out = (float*)d_out;

    char* ws = (char*)d_ws;
    const size_t SZ = (size_t)4 * NH * S_LEN * HD * sizeof(__bf16); // 8 MiB
    __bf16* Qp = (__bf16*)(ws);
    __bf16* Kp = (__bf16*)(ws + SZ);
    __bf16* Vt = (__bf16*)(ws + 2 * SZ);
    __bf16* Oa = (__bf16*)(ws + 3 * SZ);

    proj_kernel<<<dim3(S_LEN / 64, 4 * NH), 256, 0, stream>>>(q, k, v, Wq, Wk, Wv, Qp, Kp, Vt);
    attn_kernel<<<dim3(32 * 32), 512, 0, stream>>>(Qp, Kp, Vt, Oa);
    fc_kernel<<<dim3((4 * S_LEN) / 64, EMB / 64), 256, 0, stream>>>(Oa, Wfc, bfc, out);
}

// Round 10
// 97.616 us; speedup vs baseline: 1.4686x; 1.4686x over previous
//
#include <hip/hip_runtime.h>
#include <hip/hip_bf16.h>

// MultiHeadAttention B=4 S=2048 E=512 H=8 D=64, causal. Inputs fp32, output fp32.
//   proj: X @ W^T per head; Qp pre-scaled by log2(e)/8; Qp/Kp [bh][s][d], Vt [bh][d][s]
//   attn: transposed flash attention, 32x32x16 MFMA; 512-thread blocks,
//         4 kv-groups x 2 waves; P^T via cvt_pk_bf16 + IN-PLACE permlane32_swap;
//         K/V staged with global_load_lds (linear LDS dest + inverse-swizzled
//         per-lane global src, T21) -> no prefetch VGPRs, no spills (round-9 fix);
//         single-buffered per-group K/V; 4-way flash merge; LPT grid + XCD-affine bh.
//   fc:   [8192,512] @ Wfc^T + bias -> fp32 out
#define S_LEN 2048
#define EMB 512
#define NH 8
#define HD 64

#define AS1 __attribute__((address_space(1)))
#define AS3 __attribute__((address_space(3)))

typedef __bf16 bf16x8 __attribute__((ext_vector_type(8)));
typedef __bf16 bf16x4 __attribute__((ext_vector_type(4)));
typedef float f32x4 __attribute__((ext_vector_type(4)));
typedef float f32x16 __attribute__((ext_vector_type(16)));
typedef int i32x4 __attribute__((ext_vector_type(4)));

__device__ __forceinline__ unsigned swz(unsigned byteoff, unsigned row) {
    return byteoff ^ ((row & 7u) << 4);
}

// v_permlane32_swap_b32: a' = {a.lo | b.lo(placed hi)}, b' = {a.hi(placed lo) | b.hi}
__device__ __forceinline__ void plswap(int& a, int& b) {
#if __has_builtin(__builtin_amdgcn_permlane32_swap)
    auto r = __builtin_amdgcn_permlane32_swap(a, b, false, false);
    a = r[0];
    b = r[1];
#else
    asm("v_permlane32_swap_b32 %0, %1" : "+v"(a), "+v"(b));
#endif
}

__global__ __launch_bounds__(256) void proj_kernel(
    const float* __restrict__ qin, const float* __restrict__ kin, const float* __restrict__ vin,
    const float* __restrict__ Wq, const float* __restrict__ Wk, const float* __restrict__ Wv,
    __bf16* __restrict__ Qp, __bf16* __restrict__ Kp, __bf16* __restrict__ Vt)
{
    __shared__ alignas(16) unsigned char xb[3][8192]; // 64x64 bf16 tiles (q,k,v rows), swizzled
    __shared__ alignas(16) unsigned char tb[8192];    // v-proj output tile for transpose, linear
    const int bh = blockIdx.y;
    const int b = bh >> 3, h = bh & 7;
    const int sblk = blockIdx.x << 6;
    const int tid = threadIdx.x;
    const int w = tid >> 6, l = tid & 63;
    const int col = l & 15, g = l >> 4;
    const float K1 = 0.18033688011112042f; // log2(e)/8 folded into Qp

    const float* srcs[3] = {qin, kin, vin};
    #pragma unroll
    for (int p = 0; p < 3; ++p) {
        const float* src = srcs[p] + ((size_t)b * S_LEN + sblk) * EMB + h * HD;
        #pragma unroll
        for (int it = 0; it < 4; ++it) {
            int c = tid + it * 256;            // 1024 float4 chunks = 64 rows x 16
            int row = c >> 4, c4 = c & 15;
            float4 f = *reinterpret_cast<const float4*>(src + (size_t)row * EMB + c4 * 4);
            bf16x4 t;
            t[0] = (__bf16)f.x; t[1] = (__bf16)f.y; t[2] = (__bf16)f.z; t[3] = (__bf16)f.w;
            *reinterpret_cast<bf16x4*>(&xb[p][swz(row * 128 + c4 * 8, row)]) = t;
        }
    }
    __syncthreads();

    const float* Ws[3] = {Wq, Wk, Wv};
    #pragma unroll
    for (int p = 0; p < 3; ++p) {
        bf16x8 wf[4][2];
        #pragma unroll
        for (int nf = 0; nf < 4; ++nf)
            #pragma unroll
            for (int ks = 0; ks < 2; ++ks) {
                const float* base = Ws[p] + (nf * 16 + col) * HD + ks * 32 + g * 8;
                float4 f0 = *reinterpret_cast<const float4*>(base);
                float4 f1 = *reinterpret_cast<const float4*>(base + 4);
                bf16x8 r;
                r[0] = (__bf16)f0.x; r[1] = (__bf16)f0.y; r[2] = (__bf16)f0.z; r[3] = (__bf16)f0.w;
                r[4] = (__bf16)f1.x; r[5] = (__bf16)f1.y; r[6] = (__bf16)f1.z; r[7] = (__bf16)f1.w;
                wf[nf][ks] = r;
            }
        int arow = w * 16 + col;
        bf16x8 a0 = *reinterpret_cast<const bf16x8*>(&xb[p][swz(arow * 128 + g * 16, arow)]);
        bf16x8 a1 = *reinterpret_cast<const bf16x8*>(&xb[p][swz(arow * 128 + 64 + g * 16, arow)]);
        f32x4 acc[4];
        #pragma unroll
        for (int nf = 0; nf < 4; ++nf) acc[nf] = (f32x4){0.f, 0.f, 0.f, 0.f};
        #pragma unroll
        for (int nf = 0; nf < 4; ++nf) {
            acc[nf] = __builtin_amdgcn_mfma_f32_16x16x32_bf16(a0, wf[nf][0], acc[nf], 0, 0, 0);
            acc[nf] = __builtin_amdgcn_mfma_f32_16x16x32_bf16(a1, wf[nf][1], acc[nf], 0, 0, 0);
        }
        if (p < 2) {
            __bf16* dst = (p == 0 ? Qp : Kp);
            const float s0 = (p == 0) ? K1 : 1.0f; // fold softmax scale into Q
            #pragma unroll
            for (int nf = 0; nf < 4; ++nf)
                #pragma unroll
                for (int r = 0; r < 4; ++r) {
                    int srow = sblk + w * 16 + g * 4 + r;
                    dst[((size_t)bh * S_LEN + srow) * HD + nf * 16 + col] =
                        (__bf16)(acc[nf][r] * s0);
                }
        } else {
            #pragma unroll
            for (int nf = 0; nf < 4; ++nf)
                #pragma unroll
                for (int r = 0; r < 4; ++r) {
                    int srow = w * 16 + g * 4 + r;
                    *reinterpret_cast<__bf16*>(&tb[(srow * 64 + nf * 16 + col) * 2]) =
                        (__bf16)acc[nf][r];
                }
        }
    }
    __syncthreads();
    {
        int e = tid & 63, sc = tid >> 6;
        bf16x8 lo, hi;
        #pragma unroll
        for (int i = 0; i < 8; ++i)
            lo[i] = *reinterpret_cast<const __bf16*>(&tb[((sc * 16 + i) * 64 + e) * 2]);
        #pragma unroll
        for (int i = 0; i < 8; ++i)
            hi[i] = *reinterpret_cast<const __bf16*>(&tb[((sc * 16 + 8 + i) * 64 + e) * 2]);
        __bf16* dst = Vt + ((size_t)bh * HD + e) * S_LEN + sblk + sc * 16;
        *reinterpret_cast<bf16x8*>(dst) = lo;
        *reinterpret_cast<bf16x8*>(dst + 8) = hi;
    }
}

__global__ __launch_bounds__(512, 4) void attn_kernel(
    const __bf16* __restrict__ Qp, const __bf16* __restrict__ Kp,
    const __bf16* __restrict__ Vt, __bf16* __restrict__ Oa)
{
    // per-group {K 8KB, V 8KB} single-buffered; reused as merge buffers after loop
    __shared__ alignas(16) unsigned char smem[65536];
    const int l_id = blockIdx.x;
    const int bh = l_id & 31;            // XCD-affine: same-bh blocks share l%8
    const int qt = 31 - (l_id >> 5);     // LPT: longest blocks dispatched first
    const int b = bh >> 3, h = bh & 7;
    const int tid = threadIdx.x;
    const int w = tid >> 6, l = tid & 63;
    const int g2 = w >> 1, qh = w & 1;   // kv-group (0..3), q-half (0..1)
    const int c32 = l & 31, hi = l >> 5;

    unsigned char* kbg = smem + g2 * 16384;
    unsigned char* vbg = kbg + 8192;

    const unsigned char* kgb =
        reinterpret_cast<const unsigned char*>(Kp + (size_t)bh * S_LEN * HD);
    const unsigned char* vgb =
        reinterpret_cast<const unsigned char*>(Vt + (size_t)bh * HD * S_LEN);

    // global_load_lds staging (T21): linear LDS dest (wave-uniform base + lane*16),
    // inverse-swizzled per-lane global source. Slot s = qh*256 + j*64 + lane;
    // LDS[s*16] <- tile[row = s>>3][off ^ ((row&7)<<4)], so swizzled reads see tile[row][off].
    int srcoffK[4], srcoffV[4];
    #pragma unroll
    for (int j = 0; j < 4; ++j) {
        int s = qh * 256 + j * 64 + l;
        int row = s >> 3, off = (s & 7) * 16;
        int so = off ^ ((row & 7) << 4);
        srcoffK[j] = row * 128 + so;
        srcoffV[j] = row * 4096 + so;
    }

    // Q B-frag: lane holds Q[q = qt*64+qh*32+c32][d = ks*16 + hi*8 + e]
    bf16x8 qf[4];
    {
        const __bf16* qb =
            Qp + ((size_t)bh * S_LEN + qt * 64 + qh * 32 + c32) * HD + hi * 8;
        #pragma unroll
        for (int ks = 0; ks < 4; ++ks) qf[ks] = *reinterpret_cast<const bf16x8*>(qb + ks * 16);
    }
    // O^T acc: lane holds O^T[d = nf*32+(r&3)+8(r>>2)+4hi][q = c32]
    f32x16 oacc[2];
    #pragma unroll
    for (int nf = 0; nf < 2; ++nf)
        #pragma unroll
        for (int r = 0; r < 16; ++r) oacc[nf][r] = 0.f;
    float m = -1e30f, lsum = 0.f;

    if (g2 <= qt) { // prologue: stage this group's first tile (t = g2)
        const unsigned char* kg = kgb + (size_t)g2 * 8192;
        const unsigned char* vg = vgb + (size_t)g2 * 128;
        #pragma unroll
        for (int j = 0; j < 4; ++j) {
            __builtin_amdgcn_global_load_lds(
                (const AS1 unsigned int*)(kg + srcoffK[j]),
                (AS3 unsigned int*)(kbg + qh * 4096 + j * 1024), 16, 0, 0);
            __builtin_amdgcn_global_load_lds(
                (const AS1 unsigned int*)(vg + srcoffV[j]),
                (AS3 unsigned int*)(vbg + qh * 4096 + j * 1024), 16, 0, 0);
        }
    }
    __syncthreads();

    const int niter = (qt >> 2) + 1;
    #pragma unroll 1
    for (int i = 0; i < niter; ++i) {
        const int t = 4 * i + g2;
        const bool active = (t <= qt);
        const bool pfv = (t + 4 <= qt);
        if (active) {
            // S^T = K Q^T : lane holds S^T[kv = nf*32+(r&3)+8(r>>2)+4hi][q = c32]
            f32x16 sfa[2];
            #pragma unroll
            for (int nf = 0; nf < 2; ++nf)
                #pragma unroll
                for (int r = 0; r < 16; ++r) sfa[nf][r] = 0.f;
            #pragma unroll
            for (int nf = 0; nf < 2; ++nf) {
                int row = nf * 32 + c32;
                #pragma unroll
                for (int ks = 0; ks < 4; ++ks) {
                    bf16x8 kf = *reinterpret_cast<const bf16x8*>(
                        kbg + swz(row * 128 + ks * 32 + hi * 16, row));
                    sfa[nf] =
                        __builtin_amdgcn_mfma_f32_32x32x16_bf16(kf, qf[ks], sfa[nf], 0, 0, 0);
                }
            }
            if (t == qt) { // diagonal: mask kv_local > q_local
                const int qloc = qh * 32 + c32;
                #pragma unroll
                for (int nf = 0; nf < 2; ++nf)
                    #pragma unroll
                    for (int r = 0; r < 16; ++r) {
                        int kvloc = nf * 32 + (r & 3) + 8 * (r >> 2) + 4 * hi;
                        if (kvloc > qloc) sfa[nf][r] = -1e30f;
                    }
            }
            // per-q max: 31 local fmax + 1 cross-half shuffle
            float rmax = sfa[0][0];
            #pragma unroll
            for (int nf = 0; nf < 2; ++nf)
                #pragma unroll
                for (int r = 0; r < 16; ++r) rmax = fmaxf(rmax, sfa[nf][r]);
            rmax = fmaxf(rmax, __shfl_xor(rmax, 32));
            float mn = fmaxf(m, rmax);
            float sc = __builtin_exp2f(m - mn);
            m = mn;
            float rsum = 0.f;
            int wds[16];
            #pragma unroll
            for (int nf = 0; nf < 2; ++nf) {
                #pragma unroll
                for (int i2 = 0; i2 < 8; ++i2) {
                    float p0 = __builtin_exp2f(sfa[nf][2 * i2] - m);
                    float p1 = __builtin_exp2f(sfa[nf][2 * i2 + 1] - m);
                    rsum += p0 + p1;
                    asm("v_cvt_pk_bf16_f32 %0, %1, %2"
                        : "=v"(wds[nf * 8 + i2]) : "v"(p0), "v"(p1));
                }
            }
            lsum = lsum * sc + rsum;
            // P^T B-frags via IN-PLACE permlane32_swap (no extra frag registers)
            #pragma unroll
            for (int ks = 0; ks < 4; ++ks) {
                int o = (ks >> 1) * 8 + (ks & 1) * 4;
                plswap(wds[o + 0], wds[o + 2]);
                plswap(wds[o + 1], wds[o + 3]);
            }
            #pragma unroll
            for (int nf = 0; nf < 2; ++nf)
                #pragma unroll
                for (int r = 0; r < 16; ++r) oacc[nf][r] *= sc;
            // O^T += V^T P^T
            #pragma unroll
            for (int nf = 0; nf < 2; ++nf) {
                int row = nf * 32 + c32;
                #pragma unroll
                for (int ks = 0; ks < 4; ++ks) {
                    int o = (ks >> 1) * 8 + (ks & 1) * 4;
                    i32x4 pw;
                    pw[0] = wds[o]; pw[1] = wds[o + 1]; pw[2] = wds[o + 2]; pw[3] = wds[o + 3];
                    bf16x8 pfk = *reinterpret_cast<bf16x8*>(&pw);
                    bf16x8 vf = *reinterpret_cast<const bf16x8*>(
                        vbg + swz(row * 128 + ks * 32 + hi * 16, row));
                    oacc[nf] =
                        __builtin_amdgcn_mfma_f32_32x32x16_bf16(vf, pfk, oacc[nf], 0, 0, 0);
                }
            }
        }
        __syncthreads(); // all reads of this buffer done
        if (pfv) {       // refill same buffer via global_load_lds (drained at next barrier)
            const unsigned char* kg = kgb + (size_t)(t + 4) * 8192;
            const unsigned char* vg = vgb + (size_t)(t + 4) * 128;
            #pragma unroll
            for (int j = 0; j < 4; ++j) {
                __builtin_amdgcn_global_load_lds(
                    (const AS1 unsigned int*)(kg + srcoffK[j]),
                    (AS3 unsigned int*)(kbg + qh * 4096 + j * 1024), 16, 0, 0);
                __builtin_amdgcn_global_load_lds(
                    (const AS1 unsigned int*)(vg + srcoffV[j]),
                    (AS3 unsigned int*)(vbg + qh * 4096 + j * 1024), 16, 0, 0);
            }
        }
        __syncthreads(); // vmcnt drained -> staged data visible
    }

    // 4-way flash merge: groups 1..3 publish partials; group 0 merges + stores.
    float* mg = reinterpret_cast<float*>(smem);
    const int idx = (g2 - 1) * 2 + qh;
    if (g2 != 0) {
        #pragma unroll
        for (int nf = 0; nf < 2; ++nf)
            #pragma unroll
            for (int r = 0; r < 16; ++r)
                mg[idx * 2048 + (nf * 16 + r) * 64 + l] = oacc[nf][r];
        mg[12288 + idx * 128 + l] = m;
        mg[12288 + idx * 128 + 64 + l] = lsum;
    }
    __syncthreads();
    if (g2 == 0) {
        #pragma unroll 1
        for (int gg = 1; gg < 4; ++gg) {
            const int ix = (gg - 1) * 2 + qh;
            float mB = mg[12288 + ix * 128 + l];
            float lB = mg[12288 + ix * 128 + 64 + l];
            float M = fmaxf(m, mB);
            float eA = __builtin_exp2f(m - M);
            float eB = __builtin_exp2f(mB - M);
            m = M;
            lsum = eA * lsum + eB * lB;
            #pragma unroll
            for (int nf = 0; nf < 2; ++nf)
                #pragma unroll
                for (int r = 0; r < 16; ++r)
                    oacc[nf][r] = eA * oacc[nf][r] + eB * mg[ix * 2048 + (nf * 16 + r) * 64 + l];
        }
        lsum += __shfl_xor(lsum, 32);
        float inv = 1.0f / lsum;
        const int q = qt * 64 + qh * 32 + c32;
        __bf16* op = Oa + ((size_t)b * S_LEN + q) * EMB + h * HD;
        #pragma unroll
        for (int nf = 0; nf < 2; ++nf)
            #pragma unroll
            for (int rq = 0; rq < 4; ++rq) {
                bf16x4 o4;
                #pragma unroll
                for (int e = 0; e < 4; ++e) o4[e] = (__bf16)(oacc[nf][rq * 4 + e] * inv);
                *reinterpret_cast<bf16x4*>(op + nf * 32 + rq * 8 + hi * 4) = o4;
            }
    }
}

__global__ __launch_bounds__(256) void fc_kernel(
    const __bf16* __restrict__ A,   // Oattn [B*S][E] bf16
    const float* __restrict__ Wfc,  // [E][E] fp32, row-major (n, k)
    const float* __restrict__ bfc,  // [E]
    float* __restrict__ out)        // [B*S][E] fp32
{
    __shared__ alignas(16) unsigned char ab[8192]; // A tile 64x64 bf16, swizzled
    __shared__ alignas(16) unsigned char bb[8192]; // W tile 64x64 bf16, swizzled
    const int r0 = blockIdx.x << 6;
    const int n0 = blockIdx.y << 6;
    const int tid = threadIdx.x;
    const int w = tid >> 6, l = tid & 63;
    const int col = l & 15, g = l >> 4;

    f32x4 acc[4];
    #pragma unroll
    for (int nf = 0; nf < 4; ++nf) acc[nf] = (f32x4){0.f, 0.f, 0.f, 0.f};

    for (int kc = 0; kc < 8; ++kc) {
        __syncthreads();
        #pragma unroll
        for (int it = 0; it < 2; ++it) {
            int c = tid + it * 256;
            int row = c >> 3, o = (c & 7) * 16;
            uint4 d = *reinterpret_cast<const uint4*>(
                reinterpret_cast<const unsigned char*>(A) +
                ((size_t)(r0 + row) * EMB + kc * 64) * 2 + o);
            *reinterpret_cast<uint4*>(&ab[swz(row * 128 + o, row)]) = d;
        }
        #pragma unroll
        for (int it = 0; it < 4; ++it) {
            int c = tid + it * 256;
            int row = c >> 4, c4 = c & 15;
            float4 f = *reinterpret_cast<const float4*>(
                Wfc + (size_t)(n0 + row) * EMB + kc * 64 + c4 * 4);
            bf16x4 t;
            t[0] = (__bf16)f.x; t[1] = (__bf16)f.y; t[2] = (__bf16)f.z; t[3] = (__bf16)f.w;
            *reinterpret_cast<bf16x4*>(&bb[swz(row * 128 + c4 * 8, row)]) = t;
        }
        __syncthreads();
        int arow = w * 16 + col;
        #pragma unroll
        for (int ks = 0; ks < 2; ++ks) {
            bf16x8 af = *reinterpret_cast<const bf16x8*>(
                &ab[swz(arow * 128 + ks * 64 + g * 16, arow)]);
            #pragma unroll
            for (int nf = 0; nf < 4; ++nf) {
                int brow = nf * 16 + col;
                bf16x8 bf = *reinterpret_cast<const bf16x8*>(
                    &bb[swz(brow * 128 + ks * 64 + g * 16, brow)]);
                acc[nf] = __builtin_amdgcn_mfma_f32_16x16x32_bf16(af, bf, acc[nf], 0, 0, 0);
            }
        }
    }
    #pragma unroll
    for (int nf = 0; nf < 4; ++nf) {
        float bias = bfc[n0 + nf * 16 + col];
        #pragma unroll
        for (int r = 0; r < 4; ++r) {
            int row = r0 + w * 16 + g * 4 + r;
            out[(size_t)row * EMB + n0 + nf * 16 + col] = acc[nf][r] + bias;
        }
    }
}

extern "C" void kernel_launch(void* const* d_in, const int* in_sizes, int n_in,
                              void* d_out, int out_size, void* d_ws, size_t ws_size,
                              hipStream_t stream) {
    const float* q   = (const float*)d_in[0];
    const float* k   = (const float*)d_in[1];
    const float* v   = (const float*)d_in[2];
    const float* Wq  = (const float*)d_in[3];
    const float* Wk  = (const float*)d_in[4];
    const float* Wv  = (const float*)d_in[5];
    const float* Wfc = (const float*)d_in[6];
    const float* bfc = (const float*)d_in[7];
    float* out = (float*)d_out;

    char* ws = (char*)d_ws;
    const size_t SZ = (size_t)4 * NH * S_LEN * HD * sizeof(__bf16); // 8 MiB
    __bf16* Qp = (__bf16*)(ws);
    __bf16* Kp = (__bf16*)(ws + SZ);
    __bf16* Vt = (__bf16*)(ws + 2 * SZ);
    __bf16* Oa = (__bf16*)(ws + 3 * SZ);

    proj_kernel<<<dim3(S_LEN / 64, 4 * NH), 256, 0, stream>>>(q, k, v, Wq, Wk, Wv, Qp, Kp, Vt);
    attn_kernel<<<dim3(32 * 32), 512, 0, stream>>>(Qp, Kp, Vt, Oa);
    fc_kernel<<<dim3((4 * S_LEN) / 64, EMB / 64), 256, 0, stream>>>(Oa, Wfc, bfc, out);
}

// Round 11
// 96.609 us; speedup vs baseline: 1.4839x; 1.0104x over previous
//
#include <hip/hip_runtime.h>
#include <hip/hip_bf16.h>

// MultiHeadAttention B=4 S=2048 E=512 H=8 D=64, causal. Inputs fp32, output fp32.
//   proj: X @ W^T per head; Qp pre-scaled by log2(e)/8; Qp/Kp [bh][s][d], Vt [bh][d][s]
//   attn: transposed flash attention, 32x32x16 MFMA; 512-thread blocks;
//         2 kv-groups x 4 waves (wave = (qh q-half, kh kv-half)); DOUBLE-buffered
//         global_load_lds staging issued BEFORE compute (round-10 fix: drain was
//         exposed every iter), 1 barrier/iter; P^T via cvt_pk + permlane32_swap;
//         4-partial flash merge; LPT grid + XCD-affine bh.
//   fc:   [8192,512] @ Wfc^T + bias -> fp32 out
#define S_LEN 2048
#define EMB 512
#define NH 8
#define HD 64

#define AS1 __attribute__((address_space(1)))
#define AS3 __attribute__((address_space(3)))

typedef __bf16 bf16x8 __attribute__((ext_vector_type(8)));
typedef __bf16 bf16x4 __attribute__((ext_vector_type(4)));
typedef float f32x4 __attribute__((ext_vector_type(4)));
typedef float f32x16 __attribute__((ext_vector_type(16)));
typedef int i32x4 __attribute__((ext_vector_type(4)));

__device__ __forceinline__ unsigned swz(unsigned byteoff, unsigned row) {
    return byteoff ^ ((row & 7u) << 4);
}

// v_permlane32_swap_b32 (r10-validated): lanes<32: b' = a[l+32]; lanes>=32: a' = b[l-32]
__device__ __forceinline__ void plswap(int& a, int& b) {
#if __has_builtin(__builtin_amdgcn_permlane32_swap)
    auto r = __builtin_amdgcn_permlane32_swap(a, b, false, false);
    a = r[0];
    b = r[1];
#else
    asm("v_permlane32_swap_b32 %0, %1" : "+v"(a), "+v"(b));
#endif
}

__global__ __launch_bounds__(256) void proj_kernel(
    const float* __restrict__ qin, const float* __restrict__ kin, const float* __restrict__ vin,
    const float* __restrict__ Wq, const float* __restrict__ Wk, const float* __restrict__ Wv,
    __bf16* __restrict__ Qp, __bf16* __restrict__ Kp, __bf16* __restrict__ Vt)
{
    __shared__ alignas(16) unsigned char xb[3][8192]; // 64x64 bf16 tiles (q,k,v rows), swizzled
    __shared__ alignas(16) unsigned char tb[8192];    // v-proj output tile for transpose, linear
    const int bh = blockIdx.y;
    const int b = bh >> 3, h = bh & 7;
    const int sblk = blockIdx.x << 6;
    const int tid = threadIdx.x;
    const int w = tid >> 6, l = tid & 63;
    const int col = l & 15, g = l >> 4;
    const float K1 = 0.18033688011112042f; // log2(e)/8 folded into Qp

    const float* srcs[3] = {qin, kin, vin};
    #pragma unroll
    for (int p = 0; p < 3; ++p) {
        const float* src = srcs[p] + ((size_t)b * S_LEN + sblk) * EMB + h * HD;
        #pragma unroll
        for (int it = 0; it < 4; ++it) {
            int c = tid + it * 256;            // 1024 float4 chunks = 64 rows x 16
            int row = c >> 4, c4 = c & 15;
            float4 f = *reinterpret_cast<const float4*>(src + (size_t)row * EMB + c4 * 4);
            bf16x4 t;
            t[0] = (__bf16)f.x; t[1] = (__bf16)f.y; t[2] = (__bf16)f.z; t[3] = (__bf16)f.w;
            *reinterpret_cast<bf16x4*>(&xb[p][swz(row * 128 + c4 * 8, row)]) = t;
        }
    }
    __syncthreads();

    const float* Ws[3] = {Wq, Wk, Wv};
    #pragma unroll
    for (int p = 0; p < 3; ++p) {
        bf16x8 wf[4][2];
        #pragma unroll
        for (int nf = 0; nf < 4; ++nf)
            #pragma unroll
            for (int ks = 0; ks < 2; ++ks) {
                const float* base = Ws[p] + (nf * 16 + col) * HD + ks * 32 + g * 8;
                float4 f0 = *reinterpret_cast<const float4*>(base);
                float4 f1 = *reinterpret_cast<const float4*>(base + 4);
                bf16x8 r;
                r[0] = (__bf16)f0.x; r[1] = (__bf16)f0.y; r[2] = (__bf16)f0.z; r[3] = (__bf16)f0.w;
                r[4] = (__bf16)f1.x; r[5] = (__bf16)f1.y; r[6] = (__bf16)f1.z; r[7] = (__bf16)f1.w;
                wf[nf][ks] = r;
            }
        int arow = w * 16 + col;
        bf16x8 a0 = *reinterpret_cast<const bf16x8*>(&xb[p][swz(arow * 128 + g * 16, arow)]);
        bf16x8 a1 = *reinterpret_cast<const bf16x8*>(&xb[p][swz(arow * 128 + 64 + g * 16, arow)]);
        f32x4 acc[4];
        #pragma unroll
        for (int nf = 0; nf < 4; ++nf) acc[nf] = (f32x4){0.f, 0.f, 0.f, 0.f};
        #pragma unroll
        for (int nf = 0; nf < 4; ++nf) {
            acc[nf] = __builtin_amdgcn_mfma_f32_16x16x32_bf16(a0, wf[nf][0], acc[nf], 0, 0, 0);
            acc[nf] = __builtin_amdgcn_mfma_f32_16x16x32_bf16(a1, wf[nf][1], acc[nf], 0, 0, 0);
        }
        if (p < 2) {
            __bf16* dst = (p == 0 ? Qp : Kp);
            const float s0 = (p == 0) ? K1 : 1.0f; // fold softmax scale into Q
            #pragma unroll
            for (int nf = 0; nf < 4; ++nf)
                #pragma unroll
                for (int r = 0; r < 4; ++r) {
                    int srow = sblk + w * 16 + g * 4 + r;
                    dst[((size_t)bh * S_LEN + srow) * HD + nf * 16 + col] =
                        (__bf16)(acc[nf][r] * s0);
                }
        } else {
            #pragma unroll
            for (int nf = 0; nf < 4; ++nf)
                #pragma unroll
                for (int r = 0; r < 4; ++r) {
                    int srow = w * 16 + g * 4 + r;
                    *reinterpret_cast<__bf16*>(&tb[(srow * 64 + nf * 16 + col) * 2]) =
                        (__bf16)acc[nf][r];
                }
        }
    }
    __syncthreads();
    {
        int e = tid & 63, sc = tid >> 6;
        bf16x8 lo, hi;
        #pragma unroll
        for (int i = 0; i < 8; ++i)
            lo[i] = *reinterpret_cast<const __bf16*>(&tb[((sc * 16 + i) * 64 + e) * 2]);
        #pragma unroll
        for (int i = 0; i < 8; ++i)
            hi[i] = *reinterpret_cast<const __bf16*>(&tb[((sc * 16 + 8 + i) * 64 + e) * 2]);
        __bf16* dst = Vt + ((size_t)bh * HD + e) * S_LEN + sblk + sc * 16;
        *reinterpret_cast<bf16x8*>(dst) = lo;
        *reinterpret_cast<bf16x8*>(dst + 8) = hi;
    }
}

__global__ __launch_bounds__(512, 4) void attn_kernel(
    const __bf16* __restrict__ Qp, const __bf16* __restrict__ Kp,
    const __bf16* __restrict__ Vt, __bf16* __restrict__ Oa)
{
    // per-group 2x{K 8KB, V 8KB} double-buffered; reused as merge buffers after loop
    __shared__ alignas(16) unsigned char smem[65536];
    const int l_id = blockIdx.x;
    const int bh = l_id & 31;            // XCD-affine: same-bh blocks share l%8
    const int qt = 31 - (l_id >> 5);     // LPT: longest blocks dispatched first
    const int b = bh >> 3, h = bh & 7;
    const int tid = threadIdx.x;
    const int w = tid >> 6, l = tid & 63;
    const int g2 = w >> 2;               // kv-group (0/1): tiles t = 2i + g2
    const int kh = (w >> 1) & 1;         // kv-half within tile (rows kh*32..+31)
    const int qh = w & 1;                // q-half (0/1)
    const int ws4 = w & 3;               // wave idx within group (staging)
    const int c32 = l & 31, hi = l >> 5;

    unsigned char* gbase = smem + g2 * 32768; // [buf0: K|V][buf1: K|V]

    const unsigned char* kgb =
        reinterpret_cast<const unsigned char*>(Kp + (size_t)bh * S_LEN * HD);
    const unsigned char* vgb =
        reinterpret_cast<const unsigned char*>(Vt + (size_t)bh * HD * S_LEN);

    // T21 staging: linear LDS dest (wave base + lane*16), inverse-swizzled global src.
    // Slot s = ws4*128 + j*64 + lane; LDS[s*16] <- tile[row=s>>3][off ^ ((row&7)<<4)].
    int srcK[2], srcV[2];
    #pragma unroll
    for (int j = 0; j < 2; ++j) {
        int s = ws4 * 128 + j * 64 + l;
        int row = s >> 3, off = (s & 7) * 16;
        int so = off ^ ((row & 7) << 4);
        srcK[j] = row * 128 + so;
        srcV[j] = row * 4096 + so;
    }

    // Q B-frag: lane holds Q[q = qt*64+qh*32+c32][d = ks*16 + hi*8 + e]
    bf16x8 qf[4];
    {
        const __bf16* qb =
            Qp + ((size_t)bh * S_LEN + qt * 64 + qh * 32 + c32) * HD + hi * 8;
        #pragma unroll
        for (int ks = 0; ks < 4; ++ks) qf[ks] = *reinterpret_cast<const bf16x8*>(qb + ks * 16);
    }
    // O^T acc: lane holds O^T[d = nf*32+(r&3)+8(r>>2)+4hi][q = c32] over this wave's kv
    f32x16 oacc[2];
    #pragma unroll
    for (int nf = 0; nf < 2; ++nf)
        #pragma unroll
        for (int r = 0; r < 16; ++r) oacc[nf][r] = 0.f;
    float m = -1e30f, lsum = 0.f;

    if (g2 <= qt) { // prologue: stage tile g2 -> buf 0
        const unsigned char* kg = kgb + (size_t)g2 * 8192;
        const unsigned char* vg = vgb + (size_t)g2 * 128;
        #pragma unroll
        for (int j = 0; j < 2; ++j) {
            __builtin_amdgcn_global_load_lds(
                (const AS1 unsigned int*)(kg + srcK[j]),
                (AS3 unsigned int*)(gbase + ws4 * 2048 + j * 1024), 16, 0, 0);
            __builtin_amdgcn_global_load_lds(
                (const AS1 unsigned int*)(vg + srcV[j]),
                (AS3 unsigned int*)(gbase + 8192 + ws4 * 2048 + j * 1024), 16, 0, 0);
        }
    }
    __syncthreads();

    const int niter = (qt >> 1) + 1;
    #pragma unroll 1
    for (int i = 0; i < niter; ++i) {
        const int t = 2 * i + g2;
        const int cur = i & 1;
        unsigned char* kbg = gbase + cur * 16384;
        unsigned char* vbg = kbg + 8192;
        if (t + 2 <= qt) { // issue next tile BEFORE compute -> latency hides under it
            unsigned char* kbn = gbase + (cur ^ 1) * 16384;
            const unsigned char* kg = kgb + (size_t)(t + 2) * 8192;
            const unsigned char* vg = vgb + (size_t)(t + 2) * 128;
            #pragma unroll
            for (int j = 0; j < 2; ++j) {
                __builtin_amdgcn_global_load_lds(
                    (const AS1 unsigned int*)(kg + srcK[j]),
                    (AS3 unsigned int*)(kbn + ws4 * 2048 + j * 1024), 16, 0, 0);
                __builtin_amdgcn_global_load_lds(
                    (const AS1 unsigned int*)(vg + srcV[j]),
                    (AS3 unsigned int*)(kbn + 8192 + ws4 * 2048 + j * 1024), 16, 0, 0);
            }
        }
        if (t <= qt) {
            // S^T = K Q^T for kv rows kh*32..+31: lane holds
            // S^T[kv = kh*32+(r&3)+8(r>>2)+4hi][q = c32]
            f32x16 sfa;
            #pragma unroll
            for (int r = 0; r < 16; ++r) sfa[r] = 0.f;
            const int krow = kh * 32 + c32;
            #pragma unroll
            for (int ks = 0; ks < 4; ++ks) {
                bf16x8 kf = *reinterpret_cast<const bf16x8*>(
                    kbg + swz(krow * 128 + ks * 32 + hi * 16, krow));
                sfa = __builtin_amdgcn_mfma_f32_32x32x16_bf16(kf, qf[ks], sfa, 0, 0, 0);
            }
            if (t == qt) { // diagonal: mask kv_local > q_local
                const int qloc = qh * 32 + c32;
                #pragma unroll
                for (int r = 0; r < 16; ++r) {
                    int kvloc = kh * 32 + (r & 3) + 8 * (r >> 2) + 4 * hi;
                    if (kvloc > qloc) sfa[r] = -1e30f;
                }
            }
            // per-q max: 15 local fmax + 1 cross-half shuffle
            float rmax = sfa[0];
            #pragma unroll
            for (int r = 1; r < 16; ++r) rmax = fmaxf(rmax, sfa[r]);
            rmax = fmaxf(rmax, __shfl_xor(rmax, 32));
            float mn = fmaxf(m, rmax);
            float sc = __builtin_exp2f(m - mn);
            m = mn;
            float rsum = 0.f;
            int wds[8];
            #pragma unroll
            for (int i2 = 0; i2 < 8; ++i2) {
                float p0 = __builtin_exp2f(sfa[2 * i2] - m);
                float p1 = __builtin_exp2f(sfa[2 * i2 + 1] - m);
                rsum += p0 + p1;
                asm("v_cvt_pk_bf16_f32 %0, %1, %2" : "=v"(wds[i2]) : "v"(p0), "v"(p1));
            }
            lsum = lsum * sc + rsum;
            // P^T B-frags: frag ks2 = words [ks2*4 .. +3] after swap(w0,w2),swap(w1,w3)
            plswap(wds[0], wds[2]);
            plswap(wds[1], wds[3]);
            plswap(wds[4], wds[6]);
            plswap(wds[5], wds[7]);
            #pragma unroll
            for (int nf = 0; nf < 2; ++nf)
                #pragma unroll
                for (int r = 0; r < 16; ++r) oacc[nf][r] *= sc;
            // O^T += V^T P^T over this wave's 32 kv
            #pragma unroll
            for (int nf = 0; nf < 2; ++nf) {
                const int vrow = nf * 32 + c32;
                #pragma unroll
                for (int ks2 = 0; ks2 < 2; ++ks2) {
                    i32x4 pw;
                    pw[0] = wds[ks2 * 4 + 0];
                    pw[1] = wds[ks2 * 4 + 1];
                    pw[2] = wds[ks2 * 4 + 2];
                    pw[3] = wds[ks2 * 4 + 3];
                    bf16x8 pfk = *reinterpret_cast<bf16x8*>(&pw);
                    bf16x8 vf = *reinterpret_cast<const bf16x8*>(
                        vbg + swz(vrow * 128 + kh * 64 + ks2 * 32 + hi * 16, vrow));
                    oacc[nf] =
                        __builtin_amdgcn_mfma_f32_32x32x16_bf16(vf, pfk, oacc[nf], 0, 0, 0);
                }
            }
        }
        __syncthreads(); // reads of buf done + next-buf loads drained (issued pre-compute)
    }

    // 4-partial flash merge per q: partial p = g2*2 + kh; p=0 waves merge + store.
    float* mg = reinterpret_cast<float*>(smem);
    const int p = g2 * 2 + kh;
    const int idx = (p - 1) * 2 + qh;
    if (p != 0) {
        #pragma unroll
        for (int nf = 0; nf < 2; ++nf)
            #pragma unroll
            for (int r = 0; r < 16; ++r)
                mg[idx * 2048 + (nf * 16 + r) * 64 + l] = oacc[nf][r];
        mg[12288 + idx * 128 + l] = m;
        mg[12288 + idx * 128 + 64 + l] = lsum;
    }
    __syncthreads();
    if (p == 0) {
        #pragma unroll 1
        for (int gg = 1; gg < 4; ++gg) {
            const int ix = (gg - 1) * 2 + qh;
            float mB = mg[12288 + ix * 128 + l];
            float lB = mg[12288 + ix * 128 + 64 + l];
            float M = fmaxf(m, mB);
            float eA = __builtin_exp2f(m - M);
            float eB = __builtin_exp2f(mB - M);
            m = M;
            lsum = eA * lsum + eB * lB;
            #pragma unroll
            for (int nf = 0; nf < 2; ++nf)
                #pragma unroll
                for (int r = 0; r < 16; ++r)
                    oacc[nf][r] = eA * oacc[nf][r] + eB * mg[ix * 2048 + (nf * 16 + r) * 64 + l];
        }
        lsum += __shfl_xor(lsum, 32);
        float inv = 1.0f / lsum;
        const int q = qt * 64 + qh * 32 + c32;
        __bf16* op = Oa + ((size_t)b * S_LEN + q) * EMB + h * HD;
        #pragma unroll
        for (int nf = 0; nf < 2; ++nf)
            #pragma unroll
            for (int rq = 0; rq < 4; ++rq) {
                bf16x4 o4;
                #pragma unroll
                for (int e = 0; e < 4; ++e) o4[e] = (__bf16)(oacc[nf][rq * 4 + e] * inv);
                *reinterpret_cast<bf16x4*>(op + nf * 32 + rq * 8 + hi * 4) = o4;
            }
    }
}

__global__ __launch_bounds__(256) void fc_kernel(
    const __bf16* __restrict__ A,   // Oattn [B*S][E] bf16
    const float* __restrict__ Wfc,  // [E][E] fp32, row-major (n, k)
    const float* __restrict__ bfc,  // [E]
    float* __restrict__ out)        // [B*S][E] fp32
{
    __shared__ alignas(16) unsigned char ab[8192]; // A tile 64x64 bf16, swizzled
    __shared__ alignas(16) unsigned char bb[8192]; // W tile 64x64 bf16, swizzled
    const int r0 = blockIdx.x << 6;
    const int n0 = blockIdx.y << 6;
    const int tid = threadIdx.x;
    const int w = tid >> 6, l = tid & 63;
    const int col = l & 15, g = l >> 4;

    f32x4 acc[4];
    #pragma unroll
    for (int nf = 0; nf < 4; ++nf) acc[nf] = (f32x4){0.f, 0.f, 0.f, 0.f};

    for (int kc = 0; kc < 8; ++kc) {
        __syncthreads();
        #pragma unroll
        for (int it = 0; it < 2; ++it) {
            int c = tid + it * 256;
            int row = c >> 3, o = (c & 7) * 16;
            uint4 d = *reinterpret_cast<const uint4*>(
                reinterpret_cast<const unsigned char*>(A) +
                ((size_t)(r0 + row) * EMB + kc * 64) * 2 + o);
            *reinterpret_cast<uint4*>(&ab[swz(row * 128 + o, row)]) = d;
        }
        #pragma unroll
        for (int it = 0; it < 4; ++it) {
            int c = tid + it * 256;
            int row = c >> 4, c4 = c & 15;
            float4 f = *reinterpret_cast<const float4*>(
                Wfc + (size_t)(n0 + row) * EMB + kc * 64 + c4 * 4);
            bf16x4 t;
            t[0] = (__bf16)f.x; t[1] = (__bf16)f.y; t[2] = (__bf16)f.z; t[3] = (__bf16)f.w;
            *reinterpret_cast<bf16x4*>(&bb[swz(row * 128 + c4 * 8, row)]) = t;
        }
        __syncthreads();
        int arow = w * 16 + col;
        #pragma unroll
        for (int ks = 0; ks < 2; ++ks) {
            bf16x8 af = *reinterpret_cast<const bf16x8*>(
                &ab[swz(arow * 128 + ks * 64 + g * 16, arow)]);
            #pragma unroll
            for (int nf = 0; nf < 4; ++nf) {
                int brow = nf * 16 + col;
                bf16x8 bf = *reinterpret_cast<const bf16x8*>(
                    &bb[swz(brow * 128 + ks * 64 + g * 16, brow)]);
                acc[nf] = __builtin_amdgcn_mfma_f32_16x16x32_bf16(af, bf, acc[nf], 0, 0, 0);
            }
        }
    }
    #pragma unroll
    for (int nf = 0; nf < 4; ++nf) {
        float bias = bfc[n0 + nf * 16 + col];
        #pragma unroll
        for (int r = 0; r < 4; ++r) {
            int row = r0 + w * 16 + g * 4 + r;
            out[(size_t)row * EMB + n0 + nf * 16 + col] = acc[nf][r] + bias;
        }
    }
}

extern "C" void kernel_launch(void* const* d_in, const int* in_sizes, int n_in,
                              void* d_out, int out_size, void* d_ws, size_t ws_size,
                              hipStream_t stream) {
    const float* q   = (const float*)d_in[0];
    const float* k   = (const float*)d_in[1];
    const float* v   = (const float*)d_in[2];
    const float* Wq  = (const float*)d_in[3];
    const float* Wk  = (const float*)d_in[4];
    const float* Wv  = (const float*)d_in[5];
    const float* Wfc = (const float*)d_in[6];
    const float* bfc = (const float*)d_in[7];
    float* out = (float*)d_out;

    char* ws = (char*)d_ws;
    const size_t SZ = (size_t)4 * NH * S_LEN * HD * sizeof(__bf16); // 8 MiB
    __bf16* Qp = (__bf16*)(ws);
    __bf16* Kp = (__bf16*)(ws + SZ);
    __bf16* Vt = (__bf16*)(ws + 2 * SZ);
    __bf16* Oa = (__bf16*)(ws + 3 * SZ);

    proj_kernel<<<dim3(S_LEN / 64, 4 * NH), 256, 0, stream>>>(q, k, v, Wq, Wk, Wv, Qp, Kp, Vt);
    attn_kernel<<<dim3(32 * 32), 512, 0, stream>>>(Qp, Kp, Vt, Oa);
    fc_kernel<<<dim3((4 * S_LEN) / 64, EMB / 64), 256, 0, stream>>>(Oa, Wfc, bfc, out);
}

// Round 12
// 92.738 us; speedup vs baseline: 1.5458x; 1.0417x over previous
//
#include <hip/hip_runtime.h>
#include <hip/hip_bf16.h>

// MultiHeadAttention B=4 S=2048 E=512 H=8 D=64, causal. Inputs fp32, output fp32.
//   wcvt: Wfc fp32 -> bf16 (once, 512KB)
//   proj: X @ W^T per head; Qp pre-scaled by log2(e)/8; Qp/Kp [bh][s][d], Vt [bh][d][s]
//   attn: transposed flash attention, 32x32x16 MFMA; 2 kv-groups x 4 waves; dbuf
//         global_load_lds staging; P^T via cvt_pk + permlane32_swap; DEFER-MAX (T13):
//         rescale only when max grows >8 (exp2 domain); 4-partial flash merge;
//         LPT grid + XCD-affine bh.
//   fc:   128x128-tile GEMM (grid 64x4, 512 thr, 8 waves, dbuf global_load_lds,
//         32x32x16 MFMA) + bias -> fp32 out
#define S_LEN 2048
#define EMB 512
#define NH 8
#define HD 64

#define AS1 __attribute__((address_space(1)))
#define AS3 __attribute__((address_space(3)))

typedef __bf16 bf16x8 __attribute__((ext_vector_type(8)));
typedef __bf16 bf16x4 __attribute__((ext_vector_type(4)));
typedef float f32x4 __attribute__((ext_vector_type(4)));
typedef float f32x16 __attribute__((ext_vector_type(16)));
typedef int i32x4 __attribute__((ext_vector_type(4)));

__device__ __forceinline__ unsigned swz(unsigned byteoff, unsigned row) {
    return byteoff ^ ((row & 7u) << 4);
}

__device__ __forceinline__ void plswap(int& a, int& b) {
#if __has_builtin(__builtin_amdgcn_permlane32_swap)
    auto r = __builtin_amdgcn_permlane32_swap(a, b, false, false);
    a = r[0];
    b = r[1];
#else
    asm("v_permlane32_swap_b32 %0, %1" : "+v"(a), "+v"(b));
#endif
}

__global__ __launch_bounds__(256) void wcvt_kernel(
    const float* __restrict__ Wfc, __bf16* __restrict__ Wb)
{
    int i = (blockIdx.x * 256 + threadIdx.x) * 8;
    float4 f0 = *reinterpret_cast<const float4*>(Wfc + i);
    float4 f1 = *reinterpret_cast<const float4*>(Wfc + i + 4);
    bf16x8 r;
    r[0] = (__bf16)f0.x; r[1] = (__bf16)f0.y; r[2] = (__bf16)f0.z; r[3] = (__bf16)f0.w;
    r[4] = (__bf16)f1.x; r[5] = (__bf16)f1.y; r[6] = (__bf16)f1.z; r[7] = (__bf16)f1.w;
    *reinterpret_cast<bf16x8*>(Wb + i) = r;
}

__global__ __launch_bounds__(256) void proj_kernel(
    const float* __restrict__ qin, const float* __restrict__ kin, const float* __restrict__ vin,
    const float* __restrict__ Wq, const float* __restrict__ Wk, const float* __restrict__ Wv,
    __bf16* __restrict__ Qp, __bf16* __restrict__ Kp, __bf16* __restrict__ Vt)
{
    __shared__ alignas(16) unsigned char xb[3][8192]; // 64x64 bf16 tiles (q,k,v rows), swizzled
    __shared__ alignas(16) unsigned char tb[8192];    // v-proj output tile for transpose, linear
    const int bh = blockIdx.y;
    const int b = bh >> 3, h = bh & 7;
    const int sblk = blockIdx.x << 6;
    const int tid = threadIdx.x;
    const int w = tid >> 6, l = tid & 63;
    const int col = l & 15, g = l >> 4;
    const float K1 = 0.18033688011112042f; // log2(e)/8 folded into Qp

    const float* srcs[3] = {qin, kin, vin};
    #pragma unroll
    for (int p = 0; p < 3; ++p) {
        const float* src = srcs[p] + ((size_t)b * S_LEN + sblk) * EMB + h * HD;
        #pragma unroll
        for (int it = 0; it < 4; ++it) {
            int c = tid + it * 256;            // 1024 float4 chunks = 64 rows x 16
            int row = c >> 4, c4 = c & 15;
            float4 f = *reinterpret_cast<const float4*>(src + (size_t)row * EMB + c4 * 4);
            bf16x4 t;
            t[0] = (__bf16)f.x; t[1] = (__bf16)f.y; t[2] = (__bf16)f.z; t[3] = (__bf16)f.w;
            *reinterpret_cast<bf16x4*>(&xb[p][swz(row * 128 + c4 * 8, row)]) = t;
        }
    }
    __syncthreads();

    const float* Ws[3] = {Wq, Wk, Wv};
    #pragma unroll
    for (int p = 0; p < 3; ++p) {
        bf16x8 wf[4][2];
        #pragma unroll
        for (int nf = 0; nf < 4; ++nf)
            #pragma unroll
            for (int ks = 0; ks < 2; ++ks) {
                const float* base = Ws[p] + (nf * 16 + col) * HD + ks * 32 + g * 8;
                float4 f0 = *reinterpret_cast<const float4*>(base);
                float4 f1 = *reinterpret_cast<const float4*>(base + 4);
                bf16x8 r;
                r[0] = (__bf16)f0.x; r[1] = (__bf16)f0.y; r[2] = (__bf16)f0.z; r[3] = (__bf16)f0.w;
                r[4] = (__bf16)f1.x; r[5] = (__bf16)f1.y; r[6] = (__bf16)f1.z; r[7] = (__bf16)f1.w;
                wf[nf][ks] = r;
            }
        int arow = w * 16 + col;
        bf16x8 a0 = *reinterpret_cast<const bf16x8*>(&xb[p][swz(arow * 128 + g * 16, arow)]);
        bf16x8 a1 = *reinterpret_cast<const bf16x8*>(&xb[p][swz(arow * 128 + 64 + g * 16, arow)]);
        f32x4 acc[4];
        #pragma unroll
        for (int nf = 0; nf < 4; ++nf) acc[nf] = (f32x4){0.f, 0.f, 0.f, 0.f};
        #pragma unroll
        for (int nf = 0; nf < 4; ++nf) {
            acc[nf] = __builtin_amdgcn_mfma_f32_16x16x32_bf16(a0, wf[nf][0], acc[nf], 0, 0, 0);
            acc[nf] = __builtin_amdgcn_mfma_f32_16x16x32_bf16(a1, wf[nf][1], acc[nf], 0, 0, 0);
        }
        if (p < 2) {
            __bf16* dst = (p == 0 ? Qp : Kp);
            const float s0 = (p == 0) ? K1 : 1.0f; // fold softmax scale into Q
            #pragma unroll
            for (int nf = 0; nf < 4; ++nf)
                #pragma unroll
                for (int r = 0; r < 4; ++r) {
                    int srow = sblk + w * 16 + g * 4 + r;
                    dst[((size_t)bh * S_LEN + srow) * HD + nf * 16 + col] =
                        (__bf16)(acc[nf][r] * s0);
                }
        } else {
            #pragma unroll
            for (int nf = 0; nf < 4; ++nf)
                #pragma unroll
                for (int r = 0; r < 4; ++r) {
                    int srow = w * 16 + g * 4 + r;
                    *reinterpret_cast<__bf16*>(&tb[(srow * 64 + nf * 16 + col) * 2]) =
                        (__bf16)acc[nf][r];
                }
        }
    }
    __syncthreads();
    {
        int e = tid & 63, sc = tid >> 6;
        bf16x8 lo, hi;
        #pragma unroll
        for (int i = 0; i < 8; ++i)
            lo[i] = *reinterpret_cast<const __bf16*>(&tb[((sc * 16 + i) * 64 + e) * 2]);
        #pragma unroll
        for (int i = 0; i < 8; ++i)
            hi[i] = *reinterpret_cast<const __bf16*>(&tb[((sc * 16 + 8 + i) * 64 + e) * 2]);
        __bf16* dst = Vt + ((size_t)bh * HD + e) * S_LEN + sblk + sc * 16;
        *reinterpret_cast<bf16x8*>(dst) = lo;
        *reinterpret_cast<bf16x8*>(dst + 8) = hi;
    }
}

__global__ __launch_bounds__(512, 4) void attn_kernel(
    const __bf16* __restrict__ Qp, const __bf16* __restrict__ Kp,
    const __bf16* __restrict__ Vt, __bf16* __restrict__ Oa)
{
    __shared__ alignas(16) unsigned char smem[65536];
    const int l_id = blockIdx.x;
    const int bh = l_id & 31;            // XCD-affine: same-bh blocks share l%8
    const int qt = 31 - (l_id >> 5);     // LPT: longest blocks dispatched first
    const int b = bh >> 3, h = bh & 7;
    const int tid = threadIdx.x;
    const int w = tid >> 6, l = tid & 63;
    const int g2 = w >> 2;               // kv-group (0/1): tiles t = 2i + g2
    const int kh = (w >> 1) & 1;         // kv-half within tile
    const int qh = w & 1;                // q-half
    const int ws4 = w & 3;               // wave idx within group (staging)
    const int c32 = l & 31, hi = l >> 5;

    unsigned char* gbase = smem + g2 * 32768; // [buf0: K|V][buf1: K|V]

    const unsigned char* kgb =
        reinterpret_cast<const unsigned char*>(Kp + (size_t)bh * S_LEN * HD);
    const unsigned char* vgb =
        reinterpret_cast<const unsigned char*>(Vt + (size_t)bh * HD * S_LEN);

    int srcK[2], srcV[2];
    #pragma unroll
    for (int j = 0; j < 2; ++j) {
        int s = ws4 * 128 + j * 64 + l;
        int row = s >> 3, off = (s & 7) * 16;
        int so = off ^ ((row & 7) << 4);
        srcK[j] = row * 128 + so;
        srcV[j] = row * 4096 + so;
    }

    bf16x8 qf[4];
    {
        const __bf16* qb =
            Qp + ((size_t)bh * S_LEN + qt * 64 + qh * 32 + c32) * HD + hi * 8;
        #pragma unroll
        for (int ks = 0; ks < 4; ++ks) qf[ks] = *reinterpret_cast<const bf16x8*>(qb + ks * 16);
    }
    f32x16 oacc[2];
    #pragma unroll
    for (int nf = 0; nf < 2; ++nf)
        #pragma unroll
        for (int r = 0; r < 16; ++r) oacc[nf][r] = 0.f;
    float m = -1e30f, lsum = 0.f;

    if (g2 <= qt) {
        const unsigned char* kg = kgb + (size_t)g2 * 8192;
        const unsigned char* vg = vgb + (size_t)g2 * 128;
        #pragma unroll
        for (int j = 0; j < 2; ++j) {
            __builtin_amdgcn_global_load_lds(
                (const AS1 unsigned int*)(kg + srcK[j]),
                (AS3 unsigned int*)(gbase + ws4 * 2048 + j * 1024), 16, 0, 0);
            __builtin_amdgcn_global_load_lds(
                (const AS1 unsigned int*)(vg + srcV[j]),
                (AS3 unsigned int*)(gbase + 8192 + ws4 * 2048 + j * 1024), 16, 0, 0);
        }
    }
    __syncthreads();

    const int niter = (qt >> 1) + 1;
    #pragma unroll 1
    for (int i = 0; i < niter; ++i) {
        const int t = 2 * i + g2;
        const int cur = i & 1;
        unsigned char* kbg = gbase + cur * 16384;
        unsigned char* vbg = kbg + 8192;
        if (t + 2 <= qt) {
            unsigned char* kbn = gbase + (cur ^ 1) * 16384;
            const unsigned char* kg = kgb + (size_t)(t + 2) * 8192;
            const unsigned char* vg = vgb + (size_t)(t + 2) * 128;
            #pragma unroll
            for (int j = 0; j < 2; ++j) {
                __builtin_amdgcn_global_load_lds(
                    (const AS1 unsigned int*)(kg + srcK[j]),
                    (AS3 unsigned int*)(kbn + ws4 * 2048 + j * 1024), 16, 0, 0);
                __builtin_amdgcn_global_load_lds(
                    (const AS1 unsigned int*)(vg + srcV[j]),
                    (AS3 unsigned int*)(kbn + 8192 + ws4 * 2048 + j * 1024), 16, 0, 0);
            }
        }
        if (t <= qt) {
            f32x16 sfa;
            #pragma unroll
            for (int r = 0; r < 16; ++r) sfa[r] = 0.f;
            const int krow = kh * 32 + c32;
            #pragma unroll
            for (int ks = 0; ks < 4; ++ks) {
                bf16x8 kf = *reinterpret_cast<const bf16x8*>(
                    kbg + swz(krow * 128 + ks * 32 + hi * 16, krow));
                sfa = __builtin_amdgcn_mfma_f32_32x32x16_bf16(kf, qf[ks], sfa, 0, 0, 0);
            }
            if (t == qt) {
                const int qloc = qh * 32 + c32;
                #pragma unroll
                for (int r = 0; r < 16; ++r) {
                    int kvloc = kh * 32 + (r & 3) + 8 * (r >> 2) + 4 * hi;
                    if (kvloc > qloc) sfa[r] = -1e30f;
                }
            }
            // per-q max via max3 triples + 1 cross-half shuffle
            float rmax = fmaxf(fmaxf(sfa[0], sfa[1]), sfa[2]);
            rmax = fmaxf(rmax, fmaxf(sfa[3], sfa[4]));
            rmax = fmaxf(rmax, fmaxf(sfa[5], sfa[6]));
            rmax = fmaxf(rmax, fmaxf(sfa[7], sfa[8]));
            rmax = fmaxf(rmax, fmaxf(sfa[9], sfa[10]));
            rmax = fmaxf(rmax, fmaxf(sfa[11], sfa[12]));
            rmax = fmaxf(rmax, fmaxf(sfa[13], sfa[14]));
            rmax = fmaxf(rmax, sfa[15]);
            rmax = fmaxf(rmax, __shfl_xor(rmax, 32));
            // defer-max (T13): rescale only when the max grew by > 8 (P <= 2^8, bf16-safe)
            if (__any(rmax > m + 8.0f)) {
                float mn = fmaxf(m, rmax);
                float sc = __builtin_exp2f(m - mn);
                m = mn;
                lsum *= sc;
                #pragma unroll
                for (int nf = 0; nf < 2; ++nf)
                    #pragma unroll
                    for (int r = 0; r < 16; ++r) oacc[nf][r] *= sc;
            }
            float rsum = 0.f;
            int wds[8];
            #pragma unroll
            for (int i2 = 0; i2 < 8; ++i2) {
                float p0 = __builtin_exp2f(sfa[2 * i2] - m);
                float p1 = __builtin_exp2f(sfa[2 * i2 + 1] - m);
                rsum += p0 + p1;
                asm("v_cvt_pk_bf16_f32 %0, %1, %2" : "=v"(wds[i2]) : "v"(p0), "v"(p1));
            }
            lsum += rsum;
            plswap(wds[0], wds[2]);
            plswap(wds[1], wds[3]);
            plswap(wds[4], wds[6]);
            plswap(wds[5], wds[7]);
            #pragma unroll
            for (int nf = 0; nf < 2; ++nf) {
                const int vrow = nf * 32 + c32;
                #pragma unroll
                for (int ks2 = 0; ks2 < 2; ++ks2) {
                    i32x4 pw;
                    pw[0] = wds[ks2 * 4 + 0];
                    pw[1] = wds[ks2 * 4 + 1];
                    pw[2] = wds[ks2 * 4 + 2];
                    pw[3] = wds[ks2 * 4 + 3];
                    bf16x8 pfk = *reinterpret_cast<bf16x8*>(&pw);
                    bf16x8 vf = *reinterpret_cast<const bf16x8*>(
                        vbg + swz(vrow * 128 + kh * 64 + ks2 * 32 + hi * 16, vrow));
                    oacc[nf] =
                        __builtin_amdgcn_mfma_f32_32x32x16_bf16(vf, pfk, oacc[nf], 0, 0, 0);
                }
            }
        }
        __syncthreads();
    }

    // 4-partial flash merge per q: partial p = g2*2 + kh; p=0 waves merge + store.
    float* mg = reinterpret_cast<float*>(smem);
    const int p = g2 * 2 + kh;
    const int idx = (p - 1) * 2 + qh;
    if (p != 0) {
        #pragma unroll
        for (int nf = 0; nf < 2; ++nf)
            #pragma unroll
            for (int r = 0; r < 16; ++r)
                mg[idx * 2048 + (nf * 16 + r) * 64 + l] = oacc[nf][r];
        mg[12288 + idx * 128 + l] = m;
        mg[12288 + idx * 128 + 64 + l] = lsum;
    }
    __syncthreads();
    if (p == 0) {
        #pragma unroll 1
        for (int gg = 1; gg < 4; ++gg) {
            const int ix = (gg - 1) * 2 + qh;
            float mB = mg[12288 + ix * 128 + l];
            float lB = mg[12288 + ix * 128 + 64 + l];
            float M = fmaxf(m, mB);
            float eA = __builtin_exp2f(m - M);
            float eB = __builtin_exp2f(mB - M);
            m = M;
            lsum = eA * lsum + eB * lB;
            #pragma unroll
            for (int nf = 0; nf < 2; ++nf)
                #pragma unroll
                for (int r = 0; r < 16; ++r)
                    oacc[nf][r] = eA * oacc[nf][r] + eB * mg[ix * 2048 + (nf * 16 + r) * 64 + l];
        }
        lsum += __shfl_xor(lsum, 32);
        float inv = 1.0f / lsum;
        const int q = qt * 64 + qh * 32 + c32;
        __bf16* op = Oa + ((size_t)b * S_LEN + q) * EMB + h * HD;
        #pragma unroll
        for (int nf = 0; nf < 2; ++nf)
            #pragma unroll
            for (int rq = 0; rq < 4; ++rq) {
                bf16x4 o4;
                #pragma unroll
                for (int e = 0; e < 4; ++e) o4[e] = (__bf16)(oacc[nf][rq * 4 + e] * inv);
                *reinterpret_cast<bf16x4*>(op + nf * 32 + rq * 8 + hi * 4) = o4;
            }
    }
}

__global__ __launch_bounds__(512) void fc_kernel(
    const __bf16* __restrict__ A,   // Oattn [8192][512] bf16
    const __bf16* __restrict__ Wb,  // [512][512] bf16 (n, k)
    const float* __restrict__ bfc,  // [512]
    float* __restrict__ out)        // [8192][512] fp32
{
    __shared__ alignas(16) unsigned char smem[65536]; // 2 bufs x {A 16K | W 16K}
    const int tid = threadIdx.x;
    const int w = tid >> 6, l = tid & 63;
    const int c32 = l & 31, hi = l >> 5;
    const int mw = w >> 2, nw = w & 3;  // wave tile: 64m x 32n within 128x128
    const int r0 = blockIdx.x * 128, n0 = blockIdx.y * 128;

    // T21 staging offsets: slot s = w*128 + j*64 + lane over 1024 16B-chunks per matrix
    int sro[2], sof[2];
    #pragma unroll
    for (int j = 0; j < 2; ++j) {
        int s = w * 128 + j * 64 + l;
        int row = s >> 3, off = (s & 7) * 16;
        sro[j] = row;
        sof[j] = off ^ ((row & 7) << 4);
    }
    const unsigned char* Ag = reinterpret_cast<const unsigned char*>(A) + (size_t)r0 * 1024;
    const unsigned char* Wg = reinterpret_cast<const unsigned char*>(Wb) + (size_t)n0 * 1024;

    f32x16 oacc[2];
    #pragma unroll
    for (int nf = 0; nf < 2; ++nf)
        #pragma unroll
        for (int r = 0; r < 16; ++r) oacc[nf][r] = 0.f;

    // prologue: stage kc=0 -> buf0
    #pragma unroll
    for (int j = 0; j < 2; ++j) {
        __builtin_amdgcn_global_load_lds(
            (const AS1 unsigned int*)(Ag + (size_t)sro[j] * 1024 + sof[j]),
            (AS3 unsigned int*)(smem + w * 2048 + j * 1024), 16, 0, 0);
        __builtin_amdgcn_global_load_lds(
            (const AS1 unsigned int*)(Wg + (size_t)sro[j] * 1024 + sof[j]),
            (AS3 unsigned int*)(smem + 16384 + w * 2048 + j * 1024), 16, 0, 0);
    }
    __syncthreads();

    int cur = 0;
    #pragma unroll 1
    for (int kc = 0; kc < 8; ++kc) {
        if (kc + 1 < 8) { // issue next K-step's loads before compute
            unsigned char* Abn = smem + (cur ^ 1) * 32768;
            #pragma unroll
            for (int j = 0; j < 2; ++j) {
                __builtin_amdgcn_global_load_lds(
                    (const AS1 unsigned int*)(Ag + (size_t)sro[j] * 1024 + (kc + 1) * 128 + sof[j]),
                    (AS3 unsigned int*)(Abn + w * 2048 + j * 1024), 16, 0, 0);
                __builtin_amdgcn_global_load_lds(
                    (const AS1 unsigned int*)(Wg + (size_t)sro[j] * 1024 + (kc + 1) * 128 + sof[j]),
                    (AS3 unsigned int*)(Abn + 16384 + w * 2048 + j * 1024), 16, 0, 0);
            }
        }
        unsigned char* Ab = smem + cur * 32768;
        unsigned char* Wbuf = Ab + 16384;
        const int brow = nw * 32 + c32;
        #pragma unroll
        for (int ks = 0; ks < 4; ++ks) {
            bf16x8 bfg = *reinterpret_cast<const bf16x8*>(
                Wbuf + swz(brow * 128 + ks * 32 + hi * 16, brow));
            #pragma unroll
            for (int nf = 0; nf < 2; ++nf) {
                int arow = mw * 64 + nf * 32 + c32;
                bf16x8 afg = *reinterpret_cast<const bf16x8*>(
                    Ab + swz(arow * 128 + ks * 32 + hi * 16, arow));
                oacc[nf] = __builtin_amdgcn_mfma_f32_32x32x16_bf16(afg, bfg, oacc[nf], 0, 0, 0);
            }
        }
        __syncthreads();
        cur ^= 1;
    }

    const float bias = bfc[n0 + nw * 32 + c32];
    const int ncol = n0 + nw * 32 + c32;
    #pragma unroll
    for (int nf = 0; nf < 2; ++nf)
        #pragma unroll
        for (int r = 0; r < 16; ++r) {
            int mrow = r0 + mw * 64 + nf * 32 + (r & 3) + 8 * (r >> 2) + 4 * hi;
            out[(size_t)mrow * EMB + ncol] = oacc[nf][r] + bias;
        }
}

extern "C" void kernel_launch(void* const* d_in, const int* in_sizes, int n_in,
                              void* d_out, int out_size, void* d_ws, size_t ws_size,
                              hipStream_t stream) {
    const float* q   = (const float*)d_in[0];
    const float* k   = (const float*)d_in[1];
    const float* v   = (const float*)d_in[2];
    const float* Wq  = (const float*)d_in[3];
    const float* Wk  = (const float*)d_in[4];
    const float* Wv  = (const float*)d_in[5];
    const float* Wfc = (const float*)d_in[6];
    const float* bfc = (const float*)d_in[7];
    float* out = (float*)d_out;

    char* ws = (char*)d_ws;
    const size_t SZ = (size_t)4 * NH * S_LEN * HD * sizeof(__bf16); // 8 MiB
    __bf16* Qp = (__bf16*)(ws);
    __bf16* Kp = (__bf16*)(ws + SZ);
    __bf16* Vt = (__bf16*)(ws + 2 * SZ);
    __bf16* Oa = (__bf16*)(ws + 3 * SZ);
    __bf16* Wb = (__bf16*)(ws + 4 * SZ); // 512 KB

    wcvt_kernel<<<dim3(EMB * EMB / (256 * 8)), 256, 0, stream>>>(Wfc, Wb);
    proj_kernel<<<dim3(S_LEN / 64, 4 * NH), 256, 0, stream>>>(q, k, v, Wq, Wk, Wv, Qp, Kp, Vt);
    attn_kernel<<<dim3(32 * 32), 512, 0, stream>>>(Qp, Kp, Vt, Oa);
    fc_kernel<<<dim3((4 * S_LEN) / 128, EMB / 128), 512, 0, stream>>>(Oa, Wb, bfc, out);
}